// Round 1
// baseline (373.591 us; speedup 1.0000x reference)
//
#include <hip/hip_runtime.h>
#include <hip/hip_bf16.h>
#include <stdint.h>
#include <math.h>

#define NB 4
#define NS 2048
#define NHID 1024
#define NHEAD 16
#define ND 64
#define NM (NB * NS)  // 8192 rows

typedef unsigned short u16;
typedef __attribute__((ext_vector_type(8))) short bf16x8;
typedef __attribute__((ext_vector_type(4))) float f32x4;

// ---------- helpers ----------

__device__ __forceinline__ u16 f2bf(float f) {
  union { float f; unsigned u; } v; v.f = f;
  unsigned u = v.u;
  return (u16)((u + 0x7FFFu + ((u >> 16) & 1u)) >> 16);  // RNE, no NaN in data
}

// async global->LDS, 16B per lane. LDS dest must be wave-uniform base; HW adds lane*16.
__device__ __forceinline__ void gload_lds16(const u16* g, u16* l) {
  __builtin_amdgcn_global_load_lds(
      (const __attribute__((address_space(1))) void*)g,
      (__attribute__((address_space(3))) void*)l, 16, 0, 0);
}

__device__ __forceinline__ f32x4 mfma16(bf16x8 a, bf16x8 b, f32x4 c) {
  return __builtin_amdgcn_mfma_f32_16x16x32_bf16(a, b, c, 0, 0, 0);
}

// ---------- fp32 -> bf16 conversion (x + 4 weights in one launch) ----------

__global__ __launch_bounds__(256) void convert_f32_bf16(
    const float* __restrict__ x, const float* __restrict__ wq,
    const float* __restrict__ wk, const float* __restrict__ wv,
    const float* __restrict__ wo,
    u16* __restrict__ xb, u16* __restrict__ wqb, u16* __restrict__ wkb,
    u16* __restrict__ wvb, u16* __restrict__ wob) {
  const float* src; u16* dst; int n;
  switch (blockIdx.y) {
    case 0:  src = x;  dst = xb;  n = NM * NHID;   break;
    case 1:  src = wq; dst = wqb; n = NHID * NHID; break;
    case 2:  src = wk; dst = wkb; n = NHID * NHID; break;
    case 3:  src = wv; dst = wvb; n = NHID * NHID; break;
    default: src = wo; dst = wob; n = NHID * NHID; break;
  }
  int stride = gridDim.x * blockDim.x * 4;
  for (int i = (blockIdx.x * blockDim.x + threadIdx.x) * 4; i < n; i += stride) {
    float4 v = *reinterpret_cast<const float4*>(src + i);
    ushort4 o;
    o.x = f2bf(v.x); o.y = f2bf(v.y); o.z = f2bf(v.z); o.w = f2bf(v.w);
    *reinterpret_cast<ushort4*>(dst + i) = o;
  }
}

// ---------- shared GEMM mainloop: C[m][n] = sum_k A[m][k] * Bw[n][k] ----------
// 128x128 tile, BK=32, 256 threads (4 waves, 2x2), each wave 64x64 = 4x4 frags.

__device__ __forceinline__ void gemm128_mainloop(
    const u16* __restrict__ A, const u16* __restrict__ Bw, int Kdim,
    int bm, int bn, u16* As, u16* Bs, f32x4 (&acc)[4][4]) {
  const int t = threadIdx.x;
  const int w = t >> 6;
  const int l = t & 63;
  const int lr = l & 15;   // row-in-frag for A/B reads
  const int kh = l >> 4;   // k-half (8 bf16 each)
  const int wr = w >> 1, wc = w & 1;

#pragma unroll
  for (int mi = 0; mi < 4; ++mi)
#pragma unroll
    for (int ni = 0; ni < 4; ++ni) acc[mi][ni] = (f32x4){0.f, 0.f, 0.f, 0.f};

  for (int k0 = 0; k0 < Kdim; k0 += 32) {
    __syncthreads();
    // stage A[128][32] and Bw-tile[128][32] (each 8KB): linear flat layout, 16B/lane
#pragma unroll
    for (int j = 0; j < 2; ++j) {
      int idx = j * 256 + t;            // 0..511 -> flat element idx*8
      int row = idx >> 2;               // 0..127
      int kk  = (idx & 3) << 3;         // 0,8,16,24
      gload_lds16(A  + (size_t)(bm + row) * Kdim + k0 + kk, As + (size_t)(j * 256 + w * 64) * 8);
      gload_lds16(Bw + (size_t)(bn + row) * Kdim + k0 + kk, Bs + (size_t)(j * 256 + w * 64) * 8);
    }
    __syncthreads();

    bf16x8 af[4], bfr[4];
#pragma unroll
    for (int mi = 0; mi < 4; ++mi)
      af[mi] = *(const bf16x8*)&As[(wr * 64 + mi * 16 + lr) * 32 + kh * 8];
#pragma unroll
    for (int ni = 0; ni < 4; ++ni)
      bfr[ni] = *(const bf16x8*)&Bs[(wc * 64 + ni * 16 + lr) * 32 + kh * 8];
#pragma unroll
    for (int mi = 0; mi < 4; ++mi)
#pragma unroll
      for (int ni = 0; ni < 4; ++ni)
        acc[mi][ni] = mfma16(af[mi], bfr[ni], acc[mi][ni]);
  }
}

// ---------- QKV projection: x_bf [8192][1024] x W [1024][1024]^T -> Q/K [b,h,s,d], V^T [b,h,d,s] ----------

__global__ __launch_bounds__(256) void gemm_qkv(
    const u16* __restrict__ xb,
    const u16* __restrict__ wqb, const u16* __restrict__ wkb, const u16* __restrict__ wvb,
    const float* __restrict__ bq, const float* __restrict__ bk, const float* __restrict__ bv,
    u16* __restrict__ Qo, u16* __restrict__ Ko, u16* __restrict__ Vo) {
  __shared__ __align__(16) u16 As[128 * 32];
  __shared__ __align__(16) u16 Bs[128 * 32];
  const int which = blockIdx.z;
  const u16* Bw = (which == 0) ? wqb : (which == 1) ? wkb : wvb;
  const float* bias = (which == 0) ? bq : (which == 1) ? bk : bv;
  u16* outp = (which == 0) ? Qo : (which == 1) ? Ko : Vo;
  const int bm = blockIdx.x * 128, bn = blockIdx.y * 128;

  f32x4 acc[4][4];
  gemm128_mainloop(xb, Bw, NHID, bm, bn, As, Bs, acc);

  const int t = threadIdx.x, w = t >> 6, l = t & 63, lr = l & 15, hr = l >> 4;
  const int wr = w >> 1, wc = w & 1;
#pragma unroll
  for (int mi = 0; mi < 4; ++mi)
#pragma unroll
    for (int ni = 0; ni < 4; ++ni)
#pragma unroll
      for (int r = 0; r < 4; ++r) {
        int m = bm + wr * 64 + mi * 16 + hr * 4 + r;
        int n = bn + wc * 64 + ni * 16 + lr;
        float v = acc[mi][ni][r] + bias[n];
        int b = m >> 11, s = m & (NS - 1), h = n >> 6, d = n & (ND - 1);
        size_t addr;
        if (which < 2) addr = (((size_t)(b * NHEAD + h)) * NS + s) * ND + d;  // [b,h,s,d]
        else           addr = (((size_t)(b * NHEAD + h)) * ND + d) * NS + s;  // V transposed [b,h,d,s]
        outp[addr] = f2bf(v);
      }
}

// ---------- flash attention: per (q-tile of 128, head). 4 waves x 32 q-rows ----------

__global__ __launch_bounds__(256) void attn_kernel(
    const u16* __restrict__ Q, const u16* __restrict__ K,
    const u16* __restrict__ Vt, u16* __restrict__ AO) {
  __shared__ __align__(16) u16 QPs[128 * 64];  // Q tile, later reused as per-wave P buffers
  __shared__ __align__(16) u16 Ks[64 * 64];    // K tile [s_kt][d]
  __shared__ __align__(16) u16 Vs[64 * 64];    // V tile transposed [d][s_kt]

  const int t = threadIdx.x, w = t >> 6, l = t & 63;
  const int lr = l & 15, kh = l >> 4;
  const int bh = blockIdx.y;          // b*NHEAD + h
  const int q0 = blockIdx.x * 128;
  const u16* Qh = Q  + (size_t)bh * NS * ND;
  const u16* Kh = K  + (size_t)bh * NS * ND;
  const u16* Vh = Vt + (size_t)bh * NS * ND;  // [d][s]

  // stage Q tile [128][64] and hoist this wave's fragments to registers
#pragma unroll
  for (int j = 0; j < 4; ++j) {
    int idx = j * 256 + t;
    gload_lds16(Qh + (size_t)(q0 + (idx >> 3)) * ND + (idx & 7) * 8,
                QPs + (size_t)(j * 256 + w * 64) * 8);
  }
  __syncthreads();
  bf16x8 qf[2][2];
#pragma unroll
  for (int mi = 0; mi < 2; ++mi)
#pragma unroll
    for (int ks = 0; ks < 2; ++ks)
      qf[mi][ks] = *(const bf16x8*)&QPs[(w * 32 + mi * 16 + lr) * 64 + ks * 32 + kh * 8];

  f32x4 o[2][4];
  float m_i[2][4], l_i[2][4];
#pragma unroll
  for (int mi = 0; mi < 2; ++mi) {
#pragma unroll
    for (int ni = 0; ni < 4; ++ni) o[mi][ni] = (f32x4){0.f, 0.f, 0.f, 0.f};
#pragma unroll
    for (int r = 0; r < 4; ++r) { m_i[mi][r] = -INFINITY; l_i[mi][r] = 0.f; }
  }

  for (int kt = 0; kt < NS; kt += 64) {
    __syncthreads();
#pragma unroll
    for (int j = 0; j < 2; ++j) {
      int idx = j * 256 + t;
      int row = idx >> 3, col = (idx & 7) * 8;
      gload_lds16(Kh + (size_t)(kt + row) * ND + col, Ks + (size_t)(j * 256 + w * 64) * 8);
      gload_lds16(Vh + (size_t)row * NS + kt + col,   Vs + (size_t)(j * 256 + w * 64) * 8);
    }
    __syncthreads();

    // S = Q K^T  (A rows = q, B cols = kt, k = d)
    f32x4 s[2][4];
#pragma unroll
    for (int mi = 0; mi < 2; ++mi)
#pragma unroll
      for (int ni = 0; ni < 4; ++ni) s[mi][ni] = (f32x4){0.f, 0.f, 0.f, 0.f};
#pragma unroll
    for (int ks = 0; ks < 2; ++ks)
#pragma unroll
      for (int ni = 0; ni < 4; ++ni) {
        bf16x8 kf = *(const bf16x8*)&Ks[(ni * 16 + lr) * 64 + ks * 32 + kh * 8];
#pragma unroll
        for (int mi = 0; mi < 2; ++mi) s[mi][ni] = mfma16(qf[mi][ks], kf, s[mi][ni]);
      }

    // scale + per-row max (row = mi*16 + kh*4 + r, cols spread over lanes 0..15 of group)
    float pm[2][4];
#pragma unroll
    for (int mi = 0; mi < 2; ++mi)
#pragma unroll
      for (int r = 0; r < 4; ++r) {
        float mx = -INFINITY;
#pragma unroll
        for (int ni = 0; ni < 4; ++ni) {
          s[mi][ni][r] *= 0.125f;
          mx = fmaxf(mx, s[mi][ni][r]);
        }
        pm[mi][r] = mx;
      }
#pragma unroll
    for (int off = 1; off < 16; off <<= 1)
#pragma unroll
      for (int mi = 0; mi < 2; ++mi)
#pragma unroll
        for (int r = 0; r < 4; ++r)
          pm[mi][r] = fmaxf(pm[mi][r], __shfl_xor(pm[mi][r], off, 64));

    float sc[2][4];
#pragma unroll
    for (int mi = 0; mi < 2; ++mi)
#pragma unroll
      for (int r = 0; r < 4; ++r) {
        float mn = fmaxf(m_i[mi][r], pm[mi][r]);
        sc[mi][r] = __expf(m_i[mi][r] - mn);  // exp(-inf - finite) = 0 on first tile
        m_i[mi][r] = mn;
        l_i[mi][r] *= sc[mi][r];
      }
#pragma unroll
    for (int mi = 0; mi < 2; ++mi)
#pragma unroll
      for (int ni = 0; ni < 4; ++ni)
#pragma unroll
        for (int r = 0; r < 4; ++r) o[mi][ni][r] *= sc[mi][r];

    // P = exp(S - m), row-sum, write P (bf16) to this wave's LDS region
    float rs[2][4];
#pragma unroll
    for (int mi = 0; mi < 2; ++mi)
#pragma unroll
      for (int r = 0; r < 4; ++r) rs[mi][r] = 0.f;
#pragma unroll
    for (int mi = 0; mi < 2; ++mi)
#pragma unroll
      for (int ni = 0; ni < 4; ++ni)
#pragma unroll
        for (int r = 0; r < 4; ++r) {
          float p = __expf(s[mi][ni][r] - m_i[mi][r]);
          rs[mi][r] += p;
          QPs[(w * 32 + mi * 16 + kh * 4 + r) * 64 + ni * 16 + lr] = f2bf(p);
        }
#pragma unroll
    for (int off = 1; off < 16; off <<= 1)
#pragma unroll
      for (int mi = 0; mi < 2; ++mi)
#pragma unroll
        for (int r = 0; r < 4; ++r) rs[mi][r] += __shfl_xor(rs[mi][r], off, 64);
#pragma unroll
    for (int mi = 0; mi < 2; ++mi)
#pragma unroll
      for (int r = 0; r < 4; ++r) l_i[mi][r] += rs[mi][r];

    asm volatile("s_waitcnt lgkmcnt(0)" ::: "memory");  // per-wave P write->read ordering

    // O += P V  (A rows = q from P buffer, B: Vs[d][kt] so B[k][n] is contiguous)
#pragma unroll
    for (int ks = 0; ks < 2; ++ks) {
      bf16x8 pa[2];
#pragma unroll
      for (int mi = 0; mi < 2; ++mi)
        pa[mi] = *(const bf16x8*)&QPs[(w * 32 + mi * 16 + lr) * 64 + ks * 32 + kh * 8];
#pragma unroll
      for (int ni = 0; ni < 4; ++ni) {
        bf16x8 vf = *(const bf16x8*)&Vs[(ni * 16 + lr) * 64 + ks * 32 + kh * 8];
#pragma unroll
        for (int mi = 0; mi < 2; ++mi) o[mi][ni] = mfma16(pa[mi], vf, o[mi][ni]);
      }
    }
  }

  // epilogue: O /= l, write bf16 to AO[b*S + s][h*64 + d]
  const int b = bh >> 4, h = bh & (NHEAD - 1);
  float inv[2][4];
#pragma unroll
  for (int mi = 0; mi < 2; ++mi)
#pragma unroll
    for (int r = 0; r < 4; ++r) inv[mi][r] = 1.0f / l_i[mi][r];
#pragma unroll
  for (int mi = 0; mi < 2; ++mi)
#pragma unroll
    for (int ni = 0; ni < 4; ++ni)
#pragma unroll
      for (int r = 0; r < 4; ++r) {
        int srow = q0 + w * 32 + mi * 16 + kh * 4 + r;
        int col  = h * ND + ni * 16 + lr;
        AO[(size_t)(b * NS + srow) * NHID + col] = f2bf(o[mi][ni][r] * inv[mi][r]);
      }
}

// ---------- output projection: AO [8192][1024] x Wo^T + bo -> fp32 out ----------

__global__ __launch_bounds__(256) void gemm_out(
    const u16* __restrict__ AO, const u16* __restrict__ wob,
    const float* __restrict__ bo, float* __restrict__ out) {
  __shared__ __align__(16) u16 As[128 * 32];
  __shared__ __align__(16) u16 Bs[128 * 32];
  const int bm = blockIdx.x * 128, bn = blockIdx.y * 128;

  f32x4 acc[4][4];
  gemm128_mainloop(AO, wob, NHID, bm, bn, As, Bs, acc);

  const int t = threadIdx.x, w = t >> 6, l = t & 63, lr = l & 15, hr = l >> 4;
  const int wr = w >> 1, wc = w & 1;
#pragma unroll
  for (int mi = 0; mi < 4; ++mi)
#pragma unroll
    for (int ni = 0; ni < 4; ++ni)
#pragma unroll
      for (int r = 0; r < 4; ++r) {
        int m = bm + wr * 64 + mi * 16 + hr * 4 + r;
        int n = bn + wc * 64 + ni * 16 + lr;
        out[(size_t)m * NHID + n] = acc[mi][ni][r] + bo[n];
      }
}

// ---------- launch ----------

extern "C" void kernel_launch(void* const* d_in, const int* in_sizes, int n_in,
                              void* d_out, int out_size, void* d_ws, size_t ws_size,
                              hipStream_t stream) {
  const float* x  = (const float*)d_in[0];
  const float* Wq = (const float*)d_in[1];
  const float* bq = (const float*)d_in[2];
  const float* Wk = (const float*)d_in[3];
  const float* bk = (const float*)d_in[4];
  const float* Wv = (const float*)d_in[5];
  const float* bv = (const float*)d_in[6];
  const float* Wo = (const float*)d_in[7];
  const float* bo = (const float*)d_in[8];
  float* out = (float*)d_out;

  char* ws = (char*)d_ws;
  u16* xb  = (u16*)(ws + 0);         // 16 MB: x bf16 [8192][1024]
  u16* wqb = (u16*)(ws + 16777216);  // 2 MB each
  u16* wkb = (u16*)(ws + 18874368);
  u16* wvb = (u16*)(ws + 20971520);
  u16* wob = (u16*)(ws + 23068672);
  u16* Qb  = (u16*)(ws + 25165824);  // 16 MB [b,h,s,d]
  u16* Kb  = (u16*)(ws + 41943040);  // 16 MB [b,h,s,d]
  u16* Vtb = (u16*)(ws + 58720256);  // 16 MB [b,h,d,s]
  u16* AOb = (u16*)(ws + 75497472);  // 16 MB [8192][1024]

  convert_f32_bf16<<<dim3(512, 5), 256, 0, stream>>>(x, Wq, Wk, Wv, Wo, xb, wqb, wkb, wvb, wob);
  gemm_qkv<<<dim3(64, 8, 3), 256, 0, stream>>>(xb, wqb, wkb, wvb, bq, bk, bv, Qb, Kb, Vtb);
  attn_kernel<<<dim3(16, 64), 256, 0, stream>>>(Qb, Kb, Vtb, AOb);
  gemm_out<<<dim3(64, 8), 256, 0, stream>>>(AOb, wob, bo, out);
}